// Round 1
// baseline (1201.944 us; speedup 1.0000x reference)
//
#include <hip/hip_runtime.h>
#include <stddef.h>

#define K_CB   2048
#define C_DIM  64
#define HW_DIM 3136
#define B_DIM  8
#define TR     16

static const size_t OUT_FEAT_SZ = (size_t)B_DIM * C_DIM * HW_DIM;  // 1605632
static const size_t ASSIGN_SZ   = (size_t)B_DIM * K_CB * HW_DIM;   // 51380224
static const size_t DIST_SZ     = (size_t)B_DIM * HW_DIM * K_CB;   // 51380224

// ---------------------------------------------------------------------------
// Kernel A: codebook norms + transpose (cbT[c][k]) + zero the vq0 histogram.
// ---------------------------------------------------------------------------
__global__ __launch_bounds__(256) void vq_prep(const float* __restrict__ cb,
                                               float* __restrict__ cbT,
                                               float* __restrict__ cnorm,
                                               float* __restrict__ vq0) {
    const int k = blockIdx.x * 256 + threadIdx.x;               // grid = 8 -> k in [0,2048)
    const float4* row = reinterpret_cast<const float4*>(cb + (size_t)k * C_DIM);
    float n = 0.f;
#pragma unroll
    for (int i = 0; i < 16; ++i) {
        float4 v = row[i];
        n = fmaf(v.x, v.x, n); n = fmaf(v.y, v.y, n);
        n = fmaf(v.z, v.z, n); n = fmaf(v.w, v.w, n);
        cbT[(size_t)(4 * i + 0) * K_CB + k] = v.x;              // coalesced across lanes
        cbT[(size_t)(4 * i + 1) * K_CB + k] = v.y;
        cbT[(size_t)(4 * i + 2) * K_CB + k] = v.z;
        cbT[(size_t)(4 * i + 3) * K_CB + k] = v.w;
    }
    cnorm[k] = n;
    vq0[k] = 0.f;
}

// ---------------------------------------------------------------------------
// Kernel B: distance + argmin/histogram + softmax + normalized prob write.
// One WG = 16 contiguous pixels of one image (hw0 % 16 == 0).
// Thread t owns k = j*256 + t, j = 0..7  (coalesced cbT loads & dist stores).
// ---------------------------------------------------------------------------
__global__ __launch_bounds__(256, 2) void vq_main(const float* __restrict__ feat,
                                                  const float* __restrict__ cbT,
                                                  const float* __restrict__ cnorm,
                                                  float* __restrict__ dist,
                                                  float* __restrict__ assign,
                                                  float* __restrict__ vq0) {
    const int t   = threadIdx.x;
    const int n0  = blockIdx.x * TR;
    const int b   = n0 / HW_DIM;
    const int hw0 = n0 % HW_DIM;

    __shared__ float flatT[C_DIM][TR];          // feat tile, [c][r] for broadcast reads
    __shared__ float fnorm_s[TR];
    __shared__ float m_s[TR];
    __shared__ float zinv_s[TR];
    __shared__ unsigned long long redmin[TR][4];
    __shared__ float redsum[TR][4];

    // stage feat (b, c, hw0+r): 64B segments per 16 lanes
#pragma unroll
    for (int i = 0; i < 4; ++i) {
        int idx = t + 256 * i;
        int c = idx >> 4, r = idx & 15;
        flatT[c][r] = feat[((size_t)b * C_DIM + c) * HW_DIM + hw0 + r];
    }
    __syncthreads();
    if (t < TR) {
        float s = 0.f;
        for (int c = 0; c < C_DIM; ++c) { float v = flatT[c][t]; s = fmaf(v, v, s); }
        fnorm_s[t] = s;
    }
    __syncthreads();

    // ---- GEMM 1: dot(flat_r, cb_k) for 16 rows x 8 k's per thread ----
    float acc[TR][8];
#pragma unroll
    for (int r = 0; r < TR; ++r)
#pragma unroll
        for (int j = 0; j < 8; ++j) acc[r][j] = 0.f;

    for (int c = 0; c < C_DIM; ++c) {
        float cw[8];
#pragma unroll
        for (int j = 0; j < 8; ++j) cw[j] = cbT[(size_t)c * K_CB + j * 256 + t];
        float fr[TR];
#pragma unroll
        for (int r = 0; r < TR; ++r) fr[r] = flatT[c][r];   // LDS broadcast
#pragma unroll
        for (int r = 0; r < TR; ++r)
#pragma unroll
            for (int j = 0; j < 8; ++j) acc[r][j] = fmaf(fr[r], cw[j], acc[r][j]);
    }

    float cn[8];
#pragma unroll
    for (int j = 0; j < 8; ++j) cn[j] = cnorm[j * 256 + t];

    const int lane = t & 63;
    const int wid  = t >> 6;

    // ---- distance, coalesced store, per-row min (u64 key: dist bits | k) ----
#pragma unroll
    for (int r = 0; r < TR; ++r) {
        const float fn = fnorm_s[r];
        unsigned long long best = ~0ull;
        float* drow = dist + (size_t)(n0 + r) * K_CB + t;
#pragma unroll
        for (int j = 0; j < 8; ++j) {
            float d = fn + cn[j] - 2.f * acc[r][j];
            acc[r][j] = d;
            drow[j * 256] = d;
            unsigned long long key =
                ((unsigned long long)__float_as_uint(d) << 32) | (unsigned)(j * 256 + t);
            best = key < best ? key : best;     // min bits, then min k (first-index ties)
        }
#pragma unroll
        for (int msk = 1; msk < 64; msk <<= 1) {
            unsigned long long o = __shfl_xor(best, msk, 64);
            best = o < best ? o : best;
        }
        if (lane == 0) redmin[r][wid] = best;
    }
    __syncthreads();
    if (t < TR) {
        unsigned long long v = redmin[t][0];
#pragma unroll
        for (int w = 1; w < 4; ++w) { unsigned long long o = redmin[t][w]; v = o < v ? o : v; }
        m_s[t] = __uint_as_float((unsigned)(v >> 32));           // min distance (>0)
        atomicAdd(&vq0[(unsigned)(v & 0xffffffffu)], 1.0f);      // histogram
    }
    __syncthreads();

    // ---- stable softmax: e = exp((m - d) * 10), e <= 1 ----
#pragma unroll
    for (int r = 0; r < TR; ++r) {
        const float m = m_s[r];
        float s = 0.f;
#pragma unroll
        for (int j = 0; j < 8; ++j) {
            float e = __expf((m - acc[r][j]) * 10.0f);
            acc[r][j] = e;
            s += e;
        }
#pragma unroll
        for (int msk = 1; msk < 64; msk <<= 1) s += __shfl_xor(s, msk, 64);
        if (lane == 0) redsum[r][wid] = s;
    }
    __syncthreads();
    if (t < TR) {
        float s = redsum[t][0] + redsum[t][1] + redsum[t][2] + redsum[t][3];
        zinv_s[t] = 1.0f / s;
    }
    __syncthreads();

    float inv[TR];
#pragma unroll
    for (int r = 0; r < TR; ++r) inv[r] = zinv_s[r];

    // ---- write normalized prob to assignment (b, k, hw): 64B chunk per k ----
    const size_t abase = (size_t)b * K_CB * HW_DIM + hw0;
#pragma unroll
    for (int j = 0; j < 8; ++j) {
        const int k = j * 256 + t;
        float4* dst = reinterpret_cast<float4*>(assign + abase + (size_t)k * HW_DIM);
        float4 v0 = { acc[0][j] * inv[0],  acc[1][j] * inv[1],
                      acc[2][j] * inv[2],  acc[3][j] * inv[3]  };
        float4 v1 = { acc[4][j] * inv[4],  acc[5][j] * inv[5],
                      acc[6][j] * inv[6],  acc[7][j] * inv[7]  };
        float4 v2 = { acc[8][j] * inv[8],  acc[9][j] * inv[9],
                      acc[10][j] * inv[10], acc[11][j] * inv[11] };
        float4 v3 = { acc[12][j] * inv[12], acc[13][j] * inv[13],
                      acc[14][j] * inv[14], acc[15][j] * inv[15] };
        dst[0] = v0; dst[1] = v1; dst[2] = v2; dst[3] = v3;
    }
}

// ---------------------------------------------------------------------------
// Kernel C: q_feat = prob @ codebook, read in assignment layout (hw contiguous).
// WG = (b, 32 hw columns); thread: one hw column, 1/8 of k (256 rows), 64 accs.
// ---------------------------------------------------------------------------
__global__ __launch_bounds__(256) void vq_qfeat(const float* __restrict__ assign,
                                                const float* __restrict__ cb,
                                                float* __restrict__ outf) {
    const int bid = blockIdx.x;              // 8 * 98
    const int b   = bid / (HW_DIM / 32);
    const int hw0 = (bid % (HW_DIM / 32)) * 32;
    const int t   = threadIdx.x;
    const int hwi = t & 31;
    const int kq  = t >> 5;                  // 0..7 -> k segment of 256

    float qacc[64];
#pragma unroll
    for (int c = 0; c < 64; ++c) qacc[c] = 0.f;

    const float* ap = assign + (size_t)b * K_CB * HW_DIM + (size_t)(kq * 256) * HW_DIM
                      + hw0 + hwi;
    const float4* cp = reinterpret_cast<const float4*>(cb + (size_t)kq * 256 * C_DIM);

    for (int kk = 0; kk < 256; ++kk) {
        float a = ap[(size_t)kk * HW_DIM];   // coalesced across lanes
#pragma unroll
        for (int i = 0; i < 16; ++i) {
            float4 v = cp[kk * 16 + i];      // wave-uniform address (HW dedupes)
            qacc[4 * i + 0] = fmaf(a, v.x, qacc[4 * i + 0]);
            qacc[4 * i + 1] = fmaf(a, v.y, qacc[4 * i + 1]);
            qacc[4 * i + 2] = fmaf(a, v.z, qacc[4 * i + 2]);
            qacc[4 * i + 3] = fmaf(a, v.w, qacc[4 * i + 3]);
        }
    }

    __shared__ float red[32][65];            // +1 pad: conflict-free
#pragma unroll
    for (int i = 0; i < 8; ++i) {
        int lin = t + 256 * i;
        red[lin & 31][lin >> 5] = 0.f;
    }
    __syncthreads();
#pragma unroll
    for (int c = 0; c < 64; ++c) atomicAdd(&red[hwi][c], qacc[c]);
    __syncthreads();
#pragma unroll
    for (int i = 0; i < 8; ++i) {
        int lin = t + 256 * i;
        int hw = lin & 31, c = lin >> 5;
        outf[((size_t)b * C_DIM + c) * HW_DIM + hw0 + hw] = red[hw][c];
    }
}

// ---------------------------------------------------------------------------
extern "C" void kernel_launch(void* const* d_in, const int* in_sizes, int n_in,
                              void* d_out, int out_size, void* d_ws, size_t ws_size,
                              hipStream_t stream) {
    const float* feat = (const float*)d_in[0];
    const float* cb   = (const float*)d_in[1];
    // d_in[2] = cur_iter, unused (reference computes everything unconditionally)

    float* out      = (float*)d_out;
    float* out_feat = out;
    float* assign   = out + OUT_FEAT_SZ;
    float* dist     = out + OUT_FEAT_SZ + ASSIGN_SZ;
    float* vq0      = out + OUT_FEAT_SZ + ASSIGN_SZ + DIST_SZ;

    float* cbT   = (float*)d_ws;                       // 64*2048 floats = 512 KB
    float* cnorm = cbT + (size_t)C_DIM * K_CB;         // 2048 floats

    vq_prep<<<K_CB / 256, 256, 0, stream>>>(cb, cbT, cnorm, vq0);
    vq_main<<<(B_DIM * HW_DIM) / TR, 256, 0, stream>>>(feat, cbT, cnorm, dist, assign, vq0);
    vq_qfeat<<<B_DIM * (HW_DIM / 32), 256, 0, stream>>>(assign, cb, out_feat);
}

// Round 2
// 824.084 us; speedup vs baseline: 1.4585x; 1.4585x over previous
//
#include <hip/hip_runtime.h>
#include <stddef.h>

#define K_CB   2048
#define C_DIM  64
#define HW_DIM 3136
#define B_DIM  8
#define TR     16

static const size_t OUT_FEAT_SZ = (size_t)B_DIM * C_DIM * HW_DIM;  // 1605632
static const size_t ASSIGN_SZ   = (size_t)B_DIM * K_CB * HW_DIM;   // 51380224
static const size_t DIST_SZ     = (size_t)B_DIM * HW_DIM * K_CB;   // 51380224

// ---------------------------------------------------------------------------
// Kernel A: codebook norms + transpose cbT[c][k] + zero vq0 + zero out_feat.
// grid = 400 x 256.
// ---------------------------------------------------------------------------
__global__ __launch_bounds__(256) void vq_prep(const float* __restrict__ cb,
                                               float* __restrict__ cbT,
                                               float* __restrict__ cnorm,
                                               float* __restrict__ vq0,
                                               float4* __restrict__ outf4) {
    const int t = threadIdx.x, bid = blockIdx.x;
    if (bid < 8) {
        const int k = bid * 256 + t;
        const float4* row = reinterpret_cast<const float4*>(cb + (size_t)k * C_DIM);
        float n = 0.f;
#pragma unroll
        for (int i = 0; i < 16; ++i) {
            float4 v = row[i];
            n = fmaf(v.x, v.x, n); n = fmaf(v.y, v.y, n);
            n = fmaf(v.z, v.z, n); n = fmaf(v.w, v.w, n);
            cbT[(size_t)(4 * i + 0) * K_CB + k] = v.x;
            cbT[(size_t)(4 * i + 1) * K_CB + k] = v.y;
            cbT[(size_t)(4 * i + 2) * K_CB + k] = v.z;
            cbT[(size_t)(4 * i + 3) * K_CB + k] = v.w;
        }
        cnorm[k] = n;
        vq0[k] = 0.f;
    }
    const float4 z = {0.f, 0.f, 0.f, 0.f};
    const size_t nf4 = OUT_FEAT_SZ / 4;            // 401408
    size_t idx = (size_t)bid * 256 + t;
#pragma unroll
    for (int i = 0; i < 4; ++i) {
        if (idx < nf4) outf4[idx] = z;
        idx += 102400;
    }
}

// ---------------------------------------------------------------------------
// Kernel B: distance + argmin/histogram + softmax + normalized prob write.
// WG = 512 threads, 16 contiguous pixels. Thread owns k = j*512 + t, j=0..3
// -> acc[16][4] = 64 VGPRs (spill-proof).
// ---------------------------------------------------------------------------
__global__ __launch_bounds__(512, 2) void vq_main(const float* __restrict__ feat,
                                                  const float* __restrict__ cbT,
                                                  const float* __restrict__ cnorm,
                                                  float* __restrict__ dist,
                                                  float* __restrict__ assign,
                                                  float* __restrict__ vq0) {
    const int t   = threadIdx.x;
    const int n0  = blockIdx.x * TR;
    const int b   = n0 / HW_DIM;
    const int hw0 = n0 % HW_DIM;

    __shared__ float flatT[C_DIM][TR];             // [c][r], rows contiguous (64B)
    __shared__ float fnorm_s[TR];
    __shared__ float m_s[TR];
    __shared__ float zinv_s[TR];
    __shared__ unsigned long long redmin[TR][8];
    __shared__ float redsum[TR][8];

    // stage feat tile: 1024 floats, 512 threads x 2
#pragma unroll
    for (int i = 0; i < 2; ++i) {
        int idx = t + 512 * i;
        int c = idx >> 4, r = idx & 15;
        flatT[c][r] = feat[((size_t)b * C_DIM + c) * HW_DIM + hw0 + r];
    }
    __syncthreads();
    if (t < TR) {
        float s = 0.f;
        for (int c = 0; c < C_DIM; ++c) { float v = flatT[c][t]; s = fmaf(v, v, s); }
        fnorm_s[t] = s;
    }
    __syncthreads();

    // ---- GEMM 1: dot(flat_r, cb_k), 16 rows x 4 k per thread ----
    float acc[TR][4];
#pragma unroll
    for (int r = 0; r < TR; ++r)
#pragma unroll
        for (int j = 0; j < 4; ++j) acc[r][j] = 0.f;

    for (int c = 0; c < C_DIM; ++c) {
        float cw[4];
#pragma unroll
        for (int j = 0; j < 4; ++j) cw[j] = cbT[(size_t)c * K_CB + j * 512 + t];
        const float4* fT4 = reinterpret_cast<const float4*>(&flatT[c][0]);
        float4 f0 = fT4[0], f1 = fT4[1], f2 = fT4[2], f3 = fT4[3];
        const float fr[TR] = {f0.x, f0.y, f0.z, f0.w, f1.x, f1.y, f1.z, f1.w,
                              f2.x, f2.y, f2.z, f2.w, f3.x, f3.y, f3.z, f3.w};
#pragma unroll
        for (int r = 0; r < TR; ++r)
#pragma unroll
            for (int j = 0; j < 4; ++j) acc[r][j] = fmaf(fr[r], cw[j], acc[r][j]);
    }

    float cn[4];
#pragma unroll
    for (int j = 0; j < 4; ++j) cn[j] = cnorm[j * 512 + t];

    const int lane = t & 63;
    const int wid  = t >> 6;                       // 0..7

    // ---- distance, coalesced store, per-row min (u64 key: dist bits | k) ----
#pragma unroll
    for (int r = 0; r < TR; ++r) {
        const float fn = fnorm_s[r];
        unsigned long long best = ~0ull;
        float* drow = dist + (size_t)(n0 + r) * K_CB + t;
#pragma unroll
        for (int j = 0; j < 4; ++j) {
            float d = fn + cn[j] - 2.f * acc[r][j];
            acc[r][j] = d;
            drow[j * 512] = d;
            unsigned long long key =
                ((unsigned long long)__float_as_uint(d) << 32) | (unsigned)(j * 512 + t);
            best = key < best ? key : best;
        }
#pragma unroll
        for (int msk = 1; msk < 64; msk <<= 1) {
            unsigned long long o = __shfl_xor(best, msk, 64);
            best = o < best ? o : best;
        }
        if (lane == 0) redmin[r][wid] = best;
    }
    __syncthreads();
    if (t < TR) {
        unsigned long long v = redmin[t][0];
#pragma unroll
        for (int w = 1; w < 8; ++w) { unsigned long long o = redmin[t][w]; v = o < v ? o : v; }
        m_s[t] = __uint_as_float((unsigned)(v >> 32));
        atomicAdd(&vq0[(unsigned)(v & 0xffffffffu)], 1.0f);
    }
    __syncthreads();

    // ---- stable softmax: e = exp((m - d) * 10) <= 1 ----
#pragma unroll
    for (int r = 0; r < TR; ++r) {
        const float m = m_s[r];
        float s = 0.f;
#pragma unroll
        for (int j = 0; j < 4; ++j) {
            float e = __expf((m - acc[r][j]) * 10.0f);
            acc[r][j] = e;
            s += e;
        }
#pragma unroll
        for (int msk = 1; msk < 64; msk <<= 1) s += __shfl_xor(s, msk, 64);
        if (lane == 0) redsum[r][wid] = s;
    }
    __syncthreads();
    if (t < TR) {
        float s = 0.f;
#pragma unroll
        for (int w = 0; w < 8; ++w) s += redsum[t][w];
        zinv_s[t] = 1.0f / s;
    }
    __syncthreads();

    float inv[TR];
#pragma unroll
    for (int r = 0; r < TR; ++r) inv[r] = zinv_s[r];

    // ---- write normalized prob: each lane owns the full 64B line of its k ----
    const size_t abase = (size_t)b * K_CB * HW_DIM + hw0;
#pragma unroll
    for (int j = 0; j < 4; ++j) {
        const int k = j * 512 + t;
        float4* dst = reinterpret_cast<float4*>(assign + abase + (size_t)k * HW_DIM);
        float4 v0 = { acc[0][j] * inv[0],  acc[1][j] * inv[1],
                      acc[2][j] * inv[2],  acc[3][j] * inv[3]  };
        float4 v1 = { acc[4][j] * inv[4],  acc[5][j] * inv[5],
                      acc[6][j] * inv[6],  acc[7][j] * inv[7]  };
        float4 v2 = { acc[8][j] * inv[8],  acc[9][j] * inv[9],
                      acc[10][j] * inv[10], acc[11][j] * inv[11] };
        float4 v3 = { acc[12][j] * inv[12], acc[13][j] * inv[13],
                      acc[14][j] * inv[14], acc[15][j] * inv[15] };
        dst[0] = v0; dst[1] = v1; dst[2] = v2; dst[3] = v3;
    }
}

// ---------------------------------------------------------------------------
// Kernel C: q_feat = prob @ codebook. WG = 64 hw x 64 c, k split 2-way.
// Thread: 2 hw x 8 c = 16 accumulators. Codebook tile (64 k x 64 c) in LDS.
// Results accumulated into pre-zeroed out_feat via atomicAdd.
// ---------------------------------------------------------------------------
__global__ __launch_bounds__(256, 4) void vq_qfeat(const float* __restrict__ assign,
                                                   const float* __restrict__ cb,
                                                   float* __restrict__ outf) {
    __shared__ float cb_lds[64][68];               // +4 pad for write banks
    const int t   = threadIdx.x;
    const int bid = blockIdx.x;                    // 8 b * 49 tiles * 2 ks = 784
    const int ks  = bid & 1;
    const int ht  = (bid >> 1) % 49;
    const int b   = (bid >> 1) / 49;
    const int hw0 = ht * 64;
    const int hwi = t & 31;
    const int c0  = (t >> 5) * 8;                  // 8 channels per thread

    float a00 = 0.f, a01 = 0.f, a02 = 0.f, a03 = 0.f;
    float a04 = 0.f, a05 = 0.f, a06 = 0.f, a07 = 0.f;
    float a10 = 0.f, a11 = 0.f, a12 = 0.f, a13 = 0.f;
    float a14 = 0.f, a15 = 0.f, a16 = 0.f, a17 = 0.f;

    const float* ap = assign + (size_t)b * K_CB * HW_DIM + hw0 + hwi;
    const int srow = t >> 2;                       // staging: row 0..63
    const int scol = (t & 3) * 16;                 // 4 x float4 per thread

    for (int kt = 0; kt < 16; ++kt) {
        const int k0 = ks * 1024 + kt * 64;
        const float4* src = reinterpret_cast<const float4*>(cb + (size_t)(k0 + srow) * C_DIM + scol);
        float4* dstl = reinterpret_cast<float4*>(&cb_lds[srow][scol]);
#pragma unroll
        for (int q = 0; q < 4; ++q) dstl[q] = src[q];
        __syncthreads();

#pragma unroll 4
        for (int kk = 0; kk < 64; ++kk) {
            const size_t koff = (size_t)(k0 + kk) * HW_DIM;
            const float p0 = ap[koff];
            const float p1 = ap[koff + 32];
            const float4 v0 = *reinterpret_cast<const float4*>(&cb_lds[kk][c0]);
            const float4 v1 = *reinterpret_cast<const float4*>(&cb_lds[kk][c0 + 4]);
            a00 = fmaf(p0, v0.x, a00); a01 = fmaf(p0, v0.y, a01);
            a02 = fmaf(p0, v0.z, a02); a03 = fmaf(p0, v0.w, a03);
            a04 = fmaf(p0, v1.x, a04); a05 = fmaf(p0, v1.y, a05);
            a06 = fmaf(p0, v1.z, a06); a07 = fmaf(p0, v1.w, a07);
            a10 = fmaf(p1, v0.x, a10); a11 = fmaf(p1, v0.y, a11);
            a12 = fmaf(p1, v0.z, a12); a13 = fmaf(p1, v0.w, a13);
            a14 = fmaf(p1, v1.x, a14); a15 = fmaf(p1, v1.y, a15);
            a16 = fmaf(p1, v1.z, a16); a17 = fmaf(p1, v1.w, a17);
        }
        __syncthreads();
    }

    float* ob = outf + ((size_t)b * C_DIM + c0) * HW_DIM + hw0 + hwi;
    atomicAdd(ob + 0 * HW_DIM,      a00); atomicAdd(ob + 0 * HW_DIM + 32, a10);
    atomicAdd(ob + 1 * HW_DIM,      a01); atomicAdd(ob + 1 * HW_DIM + 32, a11);
    atomicAdd(ob + 2 * HW_DIM,      a02); atomicAdd(ob + 2 * HW_DIM + 32, a12);
    atomicAdd(ob + 3 * HW_DIM,      a03); atomicAdd(ob + 3 * HW_DIM + 32, a13);
    atomicAdd(ob + 4 * HW_DIM,      a04); atomicAdd(ob + 4 * HW_DIM + 32, a14);
    atomicAdd(ob + 5 * HW_DIM,      a05); atomicAdd(ob + 5 * HW_DIM + 32, a15);
    atomicAdd(ob + 6 * HW_DIM,      a06); atomicAdd(ob + 6 * HW_DIM + 32, a16);
    atomicAdd(ob + 7 * HW_DIM,      a07); atomicAdd(ob + 7 * HW_DIM + 32, a17);
}

// ---------------------------------------------------------------------------
extern "C" void kernel_launch(void* const* d_in, const int* in_sizes, int n_in,
                              void* d_out, int out_size, void* d_ws, size_t ws_size,
                              hipStream_t stream) {
    const float* feat = (const float*)d_in[0];
    const float* cb   = (const float*)d_in[1];

    float* out      = (float*)d_out;
    float* out_feat = out;
    float* assign   = out + OUT_FEAT_SZ;
    float* dist     = out + OUT_FEAT_SZ + ASSIGN_SZ;
    float* vq0      = out + OUT_FEAT_SZ + ASSIGN_SZ + DIST_SZ;

    float* cbT   = (float*)d_ws;                   // 64*2048 floats
    float* cnorm = cbT + (size_t)C_DIM * K_CB;

    vq_prep<<<400, 256, 0, stream>>>(cb, cbT, cnorm, vq0, (float4*)out_feat);
    vq_main<<<(B_DIM * HW_DIM) / TR, 512, 0, stream>>>(feat, cbT, cnorm, dist, assign, vq0);
    vq_qfeat<<<B_DIM * (HW_DIM / 64) * 2, 256, 0, stream>>>(assign, cb, out_feat);
}